// Round 14
// baseline (110.428 us; speedup 1.0000x reference)
//
#include <hip/hip_runtime.h>
#include <hip/hip_bf16.h>

typedef __bf16 bf16x8 __attribute__((ext_vector_type(8)));
typedef __bf16 bf16x4 __attribute__((ext_vector_type(4)));
typedef __bf16 bf16x2 __attribute__((ext_vector_type(2)));
typedef unsigned short u16x8 __attribute__((ext_vector_type(8)));
typedef float f32x4 __attribute__((ext_vector_type(4)));
typedef float f32x16 __attribute__((ext_vector_type(16)));

#define MFMA(a, b, c) __builtin_amdgcn_mfma_f32_16x16x32_bf16(a, b, c, 0, 0, 0)
#define MFMA32(a, b, c) __builtin_amdgcn_mfma_f32_32x32x16_bf16(a, b, c, 0, 0, 0)

#define LQ 2048
#define DD 256

static __device__ __forceinline__ float bf2f(unsigned short u) {
  union { unsigned int i; float f; } x; x.i = ((unsigned int)u) << 16; return x.f;
}
static __device__ __forceinline__ unsigned short f2bf(float f) {
  union { float f; unsigned int i; } x; x.f = f;
  unsigned int r = x.i + 0x7fffu + ((x.i >> 16) & 1u);  // RNE
  return (unsigned short)(r >> 16);
}
static __device__ __forceinline__ void gll16(const void* g, void* l) {
  __builtin_amdgcn_global_load_lds(
      (const __attribute__((address_space(1))) unsigned int*)g,
      (__attribute__((address_space(3))) unsigned int*)l, 16, 0, 0);
}
static __device__ __forceinline__ unsigned pack2(float a, float b) {
  union { bf16x2 v; unsigned u; } x;
  x.v[0] = (__bf16)a; x.v[1] = (__bf16)b;   // compiler -> v_cvt_pk_bf16_f32
  return x.u;
}

// ---------- fused weight transposes: Wq,Wk f32 [K][256] -> bf16 [256][K] ----------
__global__ void wt2_kernel(const float* __restrict__ Wq, unsigned short* __restrict__ WqT,
                           const float* __restrict__ Wk, unsigned short* __restrict__ WkT) {
  int id = blockIdx.x * 256 + threadIdx.x;
  if (id < 262144) {                 // Wq: 1024x256
    int n = id >> 10, k = id & 1023;
    WqT[id] = f2bf(Wq[k * 256 + n]);
  } else {                           // Wk: 256x256
    int j = id - 262144;
    int n = j >> 8, k = j & 255;
    WkT[j] = f2bf(Wk[k * 256 + n]);
  }
}

// ---------- projection GEMM: 32x256 tile (A read ONCE), dbuf, 1 barrier/k-step --
// out bf16[M][256] = A f32[M][Kd] @ W (+bias); W given as WT bf16 [256][Kd].
// 4 waves = 2 row-groups x 2 col-groups; wave = 16 rows x 128 cols (8 MFMA/k-step).
__global__ __launch_bounds__(256) void proj_kernel(
    const float* __restrict__ A, const unsigned short* __restrict__ WT,
    const float* __restrict__ bias, unsigned short* __restrict__ outb,
    unsigned short* __restrict__ outT, int Kd) {
  __shared__ unsigned short A_s[2][32 * 32];    // 2 x 2KB
  __shared__ unsigned short B_s[2][256 * 32];   // 2 x 16KB
  const int tid = threadIdx.x;
  const int w = tid >> 6, lane = tid & 63, g = lane >> 4, c = lane & 15;
  const int m0 = blockIdx.x * 32;
  const int wr = (w >> 1) * 16, wc = (w & 1) * 128;

  f32x4 acc[8];
  const f32x4 z4 = {0.f, 0.f, 0.f, 0.f};
#pragma unroll
  for (int j = 0; j < 8; j++) acc[j] = z4;

  // A staging: thread -> 4 f32 of row_a at k-elem offset k0a
  const int row_a = tid >> 3, k0a = (tid & 3) * 4 + ((tid >> 2) & 1) * 16;
  const unsigned swz_a = (unsigned)((row_a & 7) << 4);
  const float* asrc = A + (long)(m0 + row_a) * Kd + k0a;
  // B staging: wave w covers rows [w*64, w*64+64); 4 gll16 calls
  const int brow_w = w * 64 + (lane >> 2);

#define GLLB(buf, ks_)                                                         \
  _Pragma("unroll") for (int j = 0; j < 4; j++) {                              \
    const int brow = brow_w + j * 16;                                          \
    gll16((const char*)WT + (long)brow * (long)(Kd * 2) + (ks_) * 64 +         \
              (((lane & 3) * 16) ^ ((brow & 3) << 4)),                         \
          (char*)B_s[buf] + w * 4096 + j * 1024);                              \
  }

#define WRA(buf, p_)                                                           \
  {                                                                            \
    bf16x4 t;                                                                  \
    _Pragma("unroll") for (int jj = 0; jj < 4; jj++) t[jj] = (__bf16)(p_)[jj]; \
    *(bf16x4*)((char*)A_s[buf] +                                               \
               (((unsigned)(row_a * 64 + k0a * 2)) ^ swz_a)) = t;              \
  }

#define COMPUTE(buf)                                                           \
  {                                                                            \
    bf16x8 af, bfr[8];                                                         \
    {                                                                          \
      const int row = wr + c;                                                  \
      af = *(const bf16x8*)((char*)A_s[buf] +                                  \
           (((unsigned)(row * 64 + g * 16)) ^ ((row & 7) << 4)));              \
    }                                                                          \
    _Pragma("unroll") for (int cf = 0; cf < 8; cf++) {                         \
      const int row = wc + cf * 16 + c;                                        \
      bfr[cf] = *(const bf16x8*)((char*)B_s[buf] + row * 64 +                  \
               (((unsigned)(g * 16)) ^ ((unsigned)((row & 3) << 4))));         \
    }                                                                          \
    _Pragma("unroll") for (int cf = 0; cf < 8; cf++)                           \
      acc[cf] = MFMA(af, bfr[cf], acc[cf]);                                    \
  }

  const int nk = Kd >> 5;   // 32 (Q) or 8 (K); even, >= 8
  f32x4 pe, po;
  pe = *(const f32x4*)(asrc);
  GLLB(0, 0);
  po = *(const f32x4*)(asrc + 32);
  WRA(0, pe);
  pe = *(const f32x4*)(asrc + 64);
  __syncthreads();

  for (int t = 0; t < nk; t += 2) {
    GLLB(1, t + 1);
    WRA(1, po);                             // data t+1 (drained at prev barrier)
    if (t + 3 < nk) po = *(const f32x4*)(asrc + (t + 3) * 32);
    COMPUTE(0);
    __syncthreads();
    if (t + 2 < nk) {
      GLLB(0, t + 2);
      WRA(0, pe);                           // data t+2
      if (t + 4 < nk) pe = *(const f32x4*)(asrc + (t + 4) * 32);
    }
    COMPUTE(1);
    __syncthreads();
  }
#undef GLLB
#undef WRA
#undef COMPUTE

  // ---- epilogue: bias add, bf16 store (+ optional transposed store) ----
  const int row0 = m0 + wr + g * 4;
#pragma unroll
  for (int cf = 0; cf < 8; cf++) {
    const int col = wc + cf * 16 + c;
    const float bv = bias[col];
    unsigned short pk[4];
#pragma unroll
    for (int i = 0; i < 4; i++) {
      float v = acc[cf][i] + bv;
      pk[i] = f2bf(v);
      outb[(long)(row0 + i) * 256 + col] = pk[i];
    }
    if (outT) {
      const int b = row0 >> 11;
      const int key0 = row0 & 2047;
      unsigned long long packed = (unsigned long long)pk[0] |
                                  ((unsigned long long)pk[1] << 16) |
                                  ((unsigned long long)pk[2] << 32) |
                                  ((unsigned long long)pk[3] << 48);
      *(unsigned long long*)(outT + ((long)(b * 256 + col) * LQ + key0)) = packed;
    }
  }
}

// ---------- flash attention: swapped 32x32 MFMA, in-reg softmax (R9 loop) ------
// ALLBF only changes the epilogue write (bf16 partial for ALL splits).
template <int NSPLIT, bool ALLBF>
__global__ __launch_bounds__(256, 2) void attn_kernel(
    const unsigned short* __restrict__ Qb, const unsigned short* __restrict__ Kb,
    const unsigned short* __restrict__ KTb, unsigned short* __restrict__ Op,
    float* __restrict__ out, float* __restrict__ ML) {
  constexpr int KS = 2048 / NSPLIT;
  constexpr int NT = KS / 32;
  constexpr int NBLK = 128 * NSPLIT;
  __shared__ char Ks[2][16384];
  __shared__ char KTs[2][16384];
  const int tid = threadIdx.x;
  const int w = tid >> 6, lane = tid & 63;
  const int l5 = lane >> 5, q31 = lane & 31;
  const int lid = (blockIdx.x & 7) * (NBLK / 8) + (blockIdx.x >> 3);  // XCD-chunked
  const int ksplit = lid & (NSPLIT - 1), qg = lid / NSPLIT;
  const int b = qg >> 4;
  const long qrow0 = (long)qg * 128;
  const int kbase = ksplit * KS;
  const float CS = 0.03125f * 1.4426950408889634f;  // SCALE * log2(e)
  const float THRM = 8.0f / CS;                     // defer-max threshold (raw)

  bf16x8 qf[16];
  {
    const unsigned short* qp = Qb + (qrow0 + w * 32 + q31) * DD + l5 * 8;
#pragma unroll
    for (int s = 0; s < 16; s++) qf[s] = *(const bf16x8*)(qp + s * 16);
  }
  f32x16 o[8];
#pragma unroll
  for (int t = 0; t < 8; t++) o[t] = (f32x16)(0.f);
  float m_ = -1e30f, l_ = 0.f;

  const char* kb_b = (const char*)(Kb + (long)b * LQ * DD);
  const char* kt_b = (const char*)(KTb + (long)b * DD * LQ);

#define STAGE(buf, kt_)                                                          \
  {                                                                              \
    const int k0_ = kbase + (kt_) * 32;                                          \
    const char* kbp_ = kb_b + (long)(k0_ + q31) * 512 + l5 * 16;                 \
    _Pragma("unroll") for (int i = 0; i < 4; i++) {                              \
      const int sl = w * 4 + i;                                                  \
      gll16(kbp_ + sl * 32, Ks[buf] + sl * 1024);                                \
    }                                                                            \
    _Pragma("unroll") for (int i = 0; i < 4; i++) {                              \
      const int th = w * 4 + i;                                                  \
      gll16(kt_b + (long)((th >> 1) * 32 + q31) * 4096 + (long)k0_ * 2 +         \
                (th & 1) * 32 + l5 * 16,                                         \
            KTs[buf] + th * 1024);                                               \
    }                                                                            \
  }

  STAGE(0, 0);
  for (int kt = 0; kt < NT; kt++) {
    const int cur = kt & 1;
    __syncthreads();
    if (kt + 1 < NT) STAGE(cur ^ 1, kt + 1);

    // ---- S[key][q] = K x Q^T ----
    const char* kr = Ks[cur] + lane * 16;
    f32x16 s = (f32x16)(0.f);
#pragma unroll
    for (int sl = 0; sl < 16; sl++) {
      bf16x8 kf = *(const bf16x8*)(kr + sl * 1024);
      s = MFMA32(kf, qf[sl], s);
    }

    // ---- in-register online softmax ----
    float mx = s[0];
#pragma unroll
    for (int r = 1; r < 16; r++) mx = fmaxf(mx, s[r]);
    mx = fmaxf(mx, __shfl_xor(mx, 32));
    if (__any(mx > m_ + THRM)) {
      float mn = fmaxf(m_, mx);
      float al = exp2f((m_ - mn) * CS);
      m_ = mn;
      l_ *= al;
#pragma unroll
      for (int t = 0; t < 8; t++) o[t] *= al;
    }
    const float mCS = m_ * CS;
    float p[16];
    float ls = 0.f;
#pragma unroll
    for (int r = 0; r < 16; r++) {
      p[r] = exp2f(s[r] * CS - mCS);
      ls += p[r];
    }
    l_ += ls;

    // ---- P -> bf16 packs -> B-fragments ----
    unsigned pk[8];
#pragma unroll
    for (int j = 0; j < 8; j++) pk[j] = pack2(p[2 * j], p[2 * j + 1]);
    unsigned x0 = (unsigned)__shfl_xor((int)pk[0], 32);
    unsigned x1 = (unsigned)__shfl_xor((int)pk[1], 32);
    unsigned x2 = (unsigned)__shfl_xor((int)pk[2], 32);
    unsigned x3 = (unsigned)__shfl_xor((int)pk[3], 32);
    unsigned x4 = (unsigned)__shfl_xor((int)pk[4], 32);
    unsigned x5 = (unsigned)__shfl_xor((int)pk[5], 32);
    unsigned x6 = (unsigned)__shfl_xor((int)pk[6], 32);
    unsigned x7 = (unsigned)__shfl_xor((int)pk[7], 32);
    union { unsigned u[4]; bf16x8 v; } pf0, pf1;
    const bool hi = (l5 != 0);
    pf0.u[0] = hi ? x2 : pk[0];
    pf0.u[1] = hi ? x3 : pk[1];
    pf0.u[2] = hi ? pk[2] : x0;
    pf0.u[3] = hi ? pk[3] : x1;
    pf1.u[0] = hi ? x6 : pk[4];
    pf1.u[1] = hi ? x7 : pk[5];
    pf1.u[2] = hi ? pk[6] : x4;
    pf1.u[3] = hi ? pk[7] : x5;

    // ---- O[d][q] += V^T x P ----
    const char* vr = KTs[cur] + lane * 16;
#pragma unroll
    for (int t = 0; t < 8; t++) {
      bf16x8 v0 = *(const bf16x8*)(vr + (t * 2) * 1024);
      bf16x8 v1 = *(const bf16x8*)(vr + (t * 2 + 1) * 1024);
      o[t] = MFMA32(v0, pf0.v, o[t]);
      o[t] = MFMA32(v1, pf1.v, o[t]);
    }
  }
#undef STAGE

  l_ += __shfl_xor(l_, 32);

  const long orow = (qrow0 + w * 32 + q31) * (long)DD;
  if (!ALLBF && ksplit == NSPLIT - 1) {
    float* op = out + orow;
#pragma unroll
    for (int t = 0; t < 8; t++)
#pragma unroll
      for (int r = 0; r < 16; r++)
        op[t * 32 + (r & 3) + 8 * (r >> 2) + 4 * l5] = o[t][r];
  } else {
    unsigned short* opb = Op + (long)ksplit * (16384 * 256) + orow;
#pragma unroll
    for (int t = 0; t < 8; t++)
#pragma unroll
      for (int r = 0; r < 16; r++)
        opb[t * 32 + (r & 3) + 8 * (r >> 2) + 4 * l5] = f2bf(o[t][r]);
  }
  if (lane < 32) {
    float* mlp = ML + (long)(qg * NSPLIT + ksplit) * 256;
    mlp[w * 32 + q31] = m_;
    mlp[128 + w * 32 + q31] = l_;
  }
}

// ---------- merge the NSPLIT key-split partials + residual ----------
template <int NSPLIT, bool ALLBF>
__global__ __launch_bounds__(256) void merge_kernel(
    const unsigned short* __restrict__ Op, const float* __restrict__ ML,
    const unsigned short* __restrict__ Qb, float* __restrict__ out) {
  const float CS = 0.03125f * 1.4426950408889634f;
  const long gid = (long)blockIdx.x * 256 + threadIdx.x;
  const long idx = gid * 8;
  const int row = (int)(idx >> 8);
  const int qg = row >> 7, qr = row & 127;
  const float* mlb = ML + (long)(qg * NSPLIT) * 256;
  float mv[NSPLIT], lv[NSPLIT];
#pragma unroll
  for (int k = 0; k < NSPLIT; k++) {
    mv[k] = mlb[k * 256 + qr];
    lv[k] = mlb[k * 256 + 128 + qr];
  }
  float M = mv[0];
#pragma unroll
  for (int k = 1; k < NSPLIT; k++) M = fmaxf(M, mv[k]);
  float ek[NSPLIT], wsum = 0.f;
#pragma unroll
  for (int k = 0; k < NSPLIT; k++) {
    ek[k] = exp2f((mv[k] - M) * CS);
    wsum += ek[k] * lv[k];
  }
  const float inv = 1.0f / wsum;
  float acc[8];
  if (ALLBF) {
#pragma unroll
    for (int e = 0; e < 8; e++) acc[e] = 0.f;
#pragma unroll
    for (int k = 0; k < NSPLIT; k++) {
      u16x8 p = *(const u16x8*)(Op + (long)k * (16384 * 256) + idx);
#pragma unroll
      for (int e = 0; e < 8; e++) acc[e] += ek[k] * bf2f(p[e]);
    }
  } else {
    f32x4 pa = *(const f32x4*)(out + idx);
    f32x4 pb = *(const f32x4*)(out + idx + 4);
#pragma unroll
    for (int e = 0; e < 4; e++) {
      acc[e] = ek[NSPLIT - 1] * pa[e];
      acc[4 + e] = ek[NSPLIT - 1] * pb[e];
    }
#pragma unroll
    for (int k = 0; k < NSPLIT - 1; k++) {
      u16x8 p = *(const u16x8*)(Op + (long)k * (16384 * 256) + idx);
#pragma unroll
      for (int e = 0; e < 8; e++) acc[e] += ek[k] * bf2f(p[e]);
    }
  }
  u16x8 qv = *(const u16x8*)(Qb + idx);
  f32x4 ra, rb;
#pragma unroll
  for (int e = 0; e < 4; e++) ra[e] = acc[e] * inv + bf2f(qv[e]);
#pragma unroll
  for (int e = 0; e < 4; e++) rb[e] = acc[4 + e] * inv + bf2f(qv[4 + e]);
  *(f32x4*)(out + idx) = ra;
  *(f32x4*)(out + idx + 4) = rb;
}

extern "C" void kernel_launch(void* const* d_in, const int* in_sizes, int n_in,
                              void* d_out, int out_size, void* d_ws, size_t ws_size,
                              hipStream_t stream) {
  (void)in_sizes; (void)n_in; (void)out_size;
  const float* data1 = (const float*)d_in[0];  // [8,2048,1024]
  const float* data2 = (const float*)d_in[1];  // [8,2048,256]
  const float* Wq = (const float*)d_in[2];     // [1024,256]
  const float* bq = (const float*)d_in[3];     // [256]
  const float* Wk = (const float*)d_in[4];     // [256,256]
  const float* bk = (const float*)d_in[5];     // [256]
  float* out = (float*)d_out;                  // [8,2048,256] f32

  char* ws = (char*)d_ws;
  unsigned short* Qb  = (unsigned short*)(ws);                        // 8 MB
  unsigned short* Kb  = (unsigned short*)(ws + (8ull << 20));         // 8 MB
  unsigned short* KTb = (unsigned short*)(ws + (16ull << 20));        // 8 MB
  unsigned short* WqT = (unsigned short*)(ws + (24ull << 20));        // 512 KB
  unsigned short* WkT = (unsigned short*)(ws + (24ull << 20) + (512u << 10));  // 128 KB
  unsigned short* Op  = (unsigned short*)(ws + (25ull << 20));        // up to 4 x 8 MB

  wt2_kernel<<<dim3(1280), dim3(256), 0, stream>>>(Wq, WqT, Wk, WkT);
  proj_kernel<<<dim3(512), dim3(256), 0, stream>>>(data1, WqT, bq, Qb,
                                                   (unsigned short*)nullptr, 1024);
  proj_kernel<<<dim3(512), dim3(256), 0, stream>>>(data2, WkT, bk, Kb, KTb, 256);

  if (ws_size >= (58ull << 20)) {
    // all-bf16 partials: 4 x 8 MB at ws+25MB, ML at ws+57MB
    float* MLb = (float*)(ws + (57ull << 20));                        // 512 KB
    attn_kernel<4, true><<<dim3(512), dim3(256), 0, stream>>>(Qb, Kb, KTb, Op, out, MLb);
    merge_kernel<4, true><<<dim3(2048), dim3(256), 0, stream>>>(Op, MLb, Qb, out);
  } else if (ws_size >= (50ull << 20)) {
    float* MLb = (float*)(ws + (49ull << 20));                        // 512 KB
    attn_kernel<4, false><<<dim3(512), dim3(256), 0, stream>>>(Qb, Kb, KTb, Op, out, MLb);
    merge_kernel<4, false><<<dim3(2048), dim3(256), 0, stream>>>(Op, MLb, Qb, out);
  } else {
    float* MLb = (float*)(ws + (33ull << 20));                        // 256 KB
    attn_kernel<2, false><<<dim3(256), dim3(256), 0, stream>>>(Qb, Kb, KTb, Op, out, MLb);
    merge_kernel<2, false><<<dim3(2048), dim3(256), 0, stream>>>(Op, MLb, Qb, out);
  }
}

// Round 15
// 103.325 us; speedup vs baseline: 1.0688x; 1.0688x over previous
//
#include <hip/hip_runtime.h>
#include <hip/hip_bf16.h>

typedef __bf16 bf16x8 __attribute__((ext_vector_type(8)));
typedef __bf16 bf16x2 __attribute__((ext_vector_type(2)));
typedef unsigned short u16x8 __attribute__((ext_vector_type(8)));
typedef float f32x4 __attribute__((ext_vector_type(4)));
typedef float f32x16 __attribute__((ext_vector_type(16)));

#define MFMA(a, b, c) __builtin_amdgcn_mfma_f32_16x16x32_bf16(a, b, c, 0, 0, 0)
#define MFMA32(a, b, c) __builtin_amdgcn_mfma_f32_32x32x16_bf16(a, b, c, 0, 0, 0)

#define LQ 2048
#define DD 256

static __device__ __forceinline__ float bf2f(unsigned short u) {
  union { unsigned int i; float f; } x; x.i = ((unsigned int)u) << 16; return x.f;
}
static __device__ __forceinline__ unsigned short f2bf(float f) {
  union { float f; unsigned int i; } x; x.f = f;
  unsigned int r = x.i + 0x7fffu + ((x.i >> 16) & 1u);  // RNE
  return (unsigned short)(r >> 16);
}
static __device__ __forceinline__ void gll16(const void* g, void* l) {
  __builtin_amdgcn_global_load_lds(
      (const __attribute__((address_space(1))) unsigned int*)g,
      (__attribute__((address_space(3))) unsigned int*)l, 16, 0, 0);
}
static __device__ __forceinline__ unsigned pack2(float a, float b) {
  union { bf16x2 v; unsigned u; } x;
  x.v[0] = (__bf16)a; x.v[1] = (__bf16)b;   // compiler -> v_cvt_pk_bf16_f32
  return x.u;
}

// ---------- fused weight transposes: Wq,Wk f32 [K][256] -> bf16 [256][K] ----------
__global__ void wt2_kernel(const float* __restrict__ Wq, unsigned short* __restrict__ WqT,
                           const float* __restrict__ Wk, unsigned short* __restrict__ WkT) {
  int id = blockIdx.x * 256 + threadIdx.x;
  if (id < 262144) {                 // Wq: 1024x256
    int n = id >> 10, k = id & 1023;
    WqT[id] = f2bf(Wq[k * 256 + n]);
  } else {                           // Wk: 256x256
    int j = id - 262144;
    int n = j >> 8, k = j & 255;
    WkT[j] = f2bf(Wk[k * 256 + n]);
  }
}

// ---------- projection GEMM body: 64x128 tile, dbuf, 1 barrier/k-step (R13) ----
static __device__ __forceinline__ void proj_body(
    const float* __restrict__ A, const unsigned short* __restrict__ WT,
    const float* __restrict__ bias, unsigned short* __restrict__ outb,
    unsigned short* __restrict__ outT, int Kd, int bid,
    unsigned short* A_s /*2x64x32*/, unsigned short* B_s /*2x128x32*/) {
  const int tid = threadIdx.x;
  const int w = tid >> 6, lane = tid & 63, g = lane >> 4, c = lane & 15;
  const int m0 = (bid >> 1) * 64, n0 = (bid & 1) * 128;
  const int wr = (w >> 1) * 32, wc = (w & 1) * 64;

  f32x4 acc[2][4];
  const f32x4 z4 = {0.f, 0.f, 0.f, 0.f};
#pragma unroll
  for (int i = 0; i < 2; i++)
#pragma unroll
    for (int j = 0; j < 4; j++) acc[i][j] = z4;

  const int row_a = tid >> 2, k0a = (tid & 3) * 8;
  const unsigned swz_a = (unsigned)((row_a & 7) << 4);
  const float* asrc = A + (long)(m0 + row_a) * Kd + k0a;
  const int brow0 = w * 32 + (lane >> 2);

#define GLLB(buf, ks_)                                                         \
  _Pragma("unroll") for (int j = 0; j < 2; j++) {                              \
    const int brow = brow0 + j * 16;                                           \
    gll16((const char*)WT + (long)(n0 + brow) * (long)(Kd * 2) + (ks_) * 64 +  \
              (((lane & 3) * 16) ^ ((brow & 3) << 4)),                         \
          (char*)B_s + (buf) * 8192 + w * 2048 + j * 1024);                    \
  }

#define WRA(buf, plo, phi)                                                     \
  {                                                                            \
    bf16x8 t;                                                                  \
    _Pragma("unroll") for (int jj = 0; jj < 4; jj++) {                         \
      t[jj] = (__bf16)(plo)[jj]; t[4 + jj] = (__bf16)(phi)[jj];                \
    }                                                                          \
    *(bf16x8*)((char*)A_s + (buf) * 4096 +                                     \
               (((unsigned)(row_a * 64 + k0a * 2)) ^ swz_a)) = t;              \
  }

#define COMPUTE(buf)                                                           \
  {                                                                            \
    bf16x8 af[2], bfr[4];                                                      \
    _Pragma("unroll") for (int rf = 0; rf < 2; rf++) {                         \
      const int row = wr + rf * 16 + c;                                        \
      af[rf] = *(const bf16x8*)((char*)A_s + (buf) * 4096 +                    \
               (((unsigned)(row * 64 + g * 16)) ^ ((row & 7) << 4)));          \
    }                                                                          \
    _Pragma("unroll") for (int cf = 0; cf < 4; cf++) {                         \
      const int row = wc + cf * 16 + c;                                        \
      bfr[cf] = *(const bf16x8*)((char*)B_s + (buf) * 8192 + row * 64 +        \
               (((unsigned)(g * 16)) ^ ((unsigned)((row & 3) << 4))));         \
    }                                                                          \
    _Pragma("unroll") for (int rf = 0; rf < 2; rf++)                           \
      _Pragma("unroll") for (int cf = 0; cf < 4; cf++)                         \
        acc[rf][cf] = MFMA(af[rf], bfr[cf], acc[rf][cf]);                      \
  }

  const int nk = Kd >> 5;
  f32x4 pe0, pe1, po0, po1;
  pe0 = *(const f32x4*)(asrc);       pe1 = *(const f32x4*)(asrc + 4);
  GLLB(0, 0);
  po0 = *(const f32x4*)(asrc + 32);  po1 = *(const f32x4*)(asrc + 36);
  WRA(0, pe0, pe1);
  pe0 = *(const f32x4*)(asrc + 64);  pe1 = *(const f32x4*)(asrc + 68);
  __syncthreads();

  for (int t = 0; t < nk; t += 2) {
    GLLB(1, t + 1);
    WRA(1, po0, po1);
    if (t + 3 < nk) {
      po0 = *(const f32x4*)(asrc + (t + 3) * 32);
      po1 = *(const f32x4*)(asrc + (t + 3) * 32 + 4);
    }
    COMPUTE(0);
    __syncthreads();
    if (t + 2 < nk) {
      GLLB(0, t + 2);
      WRA(0, pe0, pe1);
      if (t + 4 < nk) {
        pe0 = *(const f32x4*)(asrc + (t + 4) * 32);
        pe1 = *(const f32x4*)(asrc + (t + 4) * 32 + 4);
      }
    }
    COMPUTE(1);
    __syncthreads();
  }
#undef GLLB
#undef WRA
#undef COMPUTE

#pragma unroll
  for (int cf = 0; cf < 4; cf++) {
    const int col = n0 + wc + cf * 16 + c;
    const float bv = bias[col];
#pragma unroll
    for (int rf = 0; rf < 2; rf++) {
      const int row0 = m0 + wr + rf * 16 + g * 4;
      unsigned short pk[4];
#pragma unroll
      for (int i = 0; i < 4; i++) {
        float v = acc[rf][cf][i] + bv;
        pk[i] = f2bf(v);
        outb[(long)(row0 + i) * 256 + col] = pk[i];
      }
      if (outT) {
        const int b = row0 >> 11;
        const int key0 = row0 & 2047;
        unsigned long long packed = (unsigned long long)pk[0] |
                                    ((unsigned long long)pk[1] << 16) |
                                    ((unsigned long long)pk[2] << 32) |
                                    ((unsigned long long)pk[3] << 48);
        *(unsigned long long*)(outT + ((long)(b * 256 + col) * LQ + key0)) = packed;
      }
    }
  }
}

// ---------- combined projection: blocks 0..511 = Q-proj, 512..1023 = K-proj ----
__global__ __launch_bounds__(256) void proj2_kernel(
    const float* __restrict__ data1, const unsigned short* __restrict__ WqT,
    const float* __restrict__ bq, unsigned short* __restrict__ Qb,
    const float* __restrict__ data2, const unsigned short* __restrict__ WkT,
    const float* __restrict__ bk, unsigned short* __restrict__ Kb,
    unsigned short* __restrict__ KTb) {
  __shared__ unsigned short A_s[2 * 64 * 32];    // 8KB
  __shared__ unsigned short B_s[2 * 128 * 32];   // 16KB
  const int bid = blockIdx.x;
  if (bid < 512) {
    proj_body(data1, WqT, bq, Qb, (unsigned short*)nullptr, 1024, bid, A_s, B_s);
  } else {
    proj_body(data2, WkT, bk, Kb, KTb, 256, bid - 512, A_s, B_s);
  }
}

// ---------- flash attention: swapped 32x32 MFMA, in-reg softmax (R9 loop) ------
// ALLBF only changes the epilogue write (bf16 partial for ALL splits).
template <int NSPLIT, bool ALLBF>
__global__ __launch_bounds__(256, 2) void attn_kernel(
    const unsigned short* __restrict__ Qb, const unsigned short* __restrict__ Kb,
    const unsigned short* __restrict__ KTb, unsigned short* __restrict__ Op,
    float* __restrict__ out, float* __restrict__ ML) {
  constexpr int KS = 2048 / NSPLIT;
  constexpr int NT = KS / 32;
  constexpr int NBLK = 128 * NSPLIT;
  __shared__ char Ks[2][16384];
  __shared__ char KTs[2][16384];
  const int tid = threadIdx.x;
  const int w = tid >> 6, lane = tid & 63;
  const int l5 = lane >> 5, q31 = lane & 31;
  const int lid = (blockIdx.x & 7) * (NBLK / 8) + (blockIdx.x >> 3);  // XCD-chunked
  const int ksplit = lid & (NSPLIT - 1), qg = lid / NSPLIT;
  const int b = qg >> 4;
  const long qrow0 = (long)qg * 128;
  const int kbase = ksplit * KS;
  const float CS = 0.03125f * 1.4426950408889634f;  // SCALE * log2(e)
  const float THRM = 8.0f / CS;                     // defer-max threshold (raw)

  bf16x8 qf[16];
  {
    const unsigned short* qp = Qb + (qrow0 + w * 32 + q31) * DD + l5 * 8;
#pragma unroll
    for (int s = 0; s < 16; s++) qf[s] = *(const bf16x8*)(qp + s * 16);
  }
  f32x16 o[8];
#pragma unroll
  for (int t = 0; t < 8; t++) o[t] = (f32x16)(0.f);
  float m_ = -1e30f, l_ = 0.f;

  const char* kb_b = (const char*)(Kb + (long)b * LQ * DD);
  const char* kt_b = (const char*)(KTb + (long)b * DD * LQ);

#define STAGE(buf, kt_)                                                          \
  {                                                                              \
    const int k0_ = kbase + (kt_) * 32;                                          \
    const char* kbp_ = kb_b + (long)(k0_ + q31) * 512 + l5 * 16;                 \
    _Pragma("unroll") for (int i = 0; i < 4; i++) {                              \
      const int sl = w * 4 + i;                                                  \
      gll16(kbp_ + sl * 32, Ks[buf] + sl * 1024);                                \
    }                                                                            \
    _Pragma("unroll") for (int i = 0; i < 4; i++) {                              \
      const int th = w * 4 + i;                                                  \
      gll16(kt_b + (long)((th >> 1) * 32 + q31) * 4096 + (long)k0_ * 2 +         \
                (th & 1) * 32 + l5 * 16,                                         \
            KTs[buf] + th * 1024);                                               \
    }                                                                            \
  }

  STAGE(0, 0);
  for (int kt = 0; kt < NT; kt++) {
    const int cur = kt & 1;
    __syncthreads();
    if (kt + 1 < NT) STAGE(cur ^ 1, kt + 1);

    // ---- S[key][q] = K x Q^T ----
    const char* kr = Ks[cur] + lane * 16;
    f32x16 s = (f32x16)(0.f);
#pragma unroll
    for (int sl = 0; sl < 16; sl++) {
      bf16x8 kf = *(const bf16x8*)(kr + sl * 1024);
      s = MFMA32(kf, qf[sl], s);
    }

    // ---- in-register online softmax ----
    float mx = s[0];
#pragma unroll
    for (int r = 1; r < 16; r++) mx = fmaxf(mx, s[r]);
    mx = fmaxf(mx, __shfl_xor(mx, 32));
    if (__any(mx > m_ + THRM)) {
      float mn = fmaxf(m_, mx);
      float al = exp2f((m_ - mn) * CS);
      m_ = mn;
      l_ *= al;
#pragma unroll
      for (int t = 0; t < 8; t++) o[t] *= al;
    }
    const float mCS = m_ * CS;
    float p[16];
    float ls = 0.f;
#pragma unroll
    for (int r = 0; r < 16; r++) {
      p[r] = exp2f(s[r] * CS - mCS);
      ls += p[r];
    }
    l_ += ls;

    // ---- P -> bf16 packs -> B-fragments ----
    unsigned pk[8];
#pragma unroll
    for (int j = 0; j < 8; j++) pk[j] = pack2(p[2 * j], p[2 * j + 1]);
    unsigned x0 = (unsigned)__shfl_xor((int)pk[0], 32);
    unsigned x1 = (unsigned)__shfl_xor((int)pk[1], 32);
    unsigned x2 = (unsigned)__shfl_xor((int)pk[2], 32);
    unsigned x3 = (unsigned)__shfl_xor((int)pk[3], 32);
    unsigned x4 = (unsigned)__shfl_xor((int)pk[4], 32);
    unsigned x5 = (unsigned)__shfl_xor((int)pk[5], 32);
    unsigned x6 = (unsigned)__shfl_xor((int)pk[6], 32);
    unsigned x7 = (unsigned)__shfl_xor((int)pk[7], 32);
    union { unsigned u[4]; bf16x8 v; } pf0, pf1;
    const bool hi = (l5 != 0);
    pf0.u[0] = hi ? x2 : pk[0];
    pf0.u[1] = hi ? x3 : pk[1];
    pf0.u[2] = hi ? pk[2] : x0;
    pf0.u[3] = hi ? pk[3] : x1;
    pf1.u[0] = hi ? x6 : pk[4];
    pf1.u[1] = hi ? x7 : pk[5];
    pf1.u[2] = hi ? pk[6] : x4;
    pf1.u[3] = hi ? pk[7] : x5;

    // ---- O[d][q] += V^T x P ----
    const char* vr = KTs[cur] + lane * 16;
#pragma unroll
    for (int t = 0; t < 8; t++) {
      bf16x8 v0 = *(const bf16x8*)(vr + (t * 2) * 1024);
      bf16x8 v1 = *(const bf16x8*)(vr + (t * 2 + 1) * 1024);
      o[t] = MFMA32(v0, pf0.v, o[t]);
      o[t] = MFMA32(v1, pf1.v, o[t]);
    }
  }
#undef STAGE

  l_ += __shfl_xor(l_, 32);

  const long orow = (qrow0 + w * 32 + q31) * (long)DD;
  if (!ALLBF && ksplit == NSPLIT - 1) {
    float* op = out + orow;
#pragma unroll
    for (int t = 0; t < 8; t++)
#pragma unroll
      for (int r = 0; r < 16; r++)
        op[t * 32 + (r & 3) + 8 * (r >> 2) + 4 * l5] = o[t][r];
  } else {
    unsigned short* opb = Op + (long)ksplit * (16384 * 256) + orow;
#pragma unroll
    for (int t = 0; t < 8; t++)
#pragma unroll
      for (int r = 0; r < 16; r++)
        opb[t * 32 + (r & 3) + 8 * (r >> 2) + 4 * l5] = f2bf(o[t][r]);
  }
  if (lane < 32) {
    float* mlp = ML + (long)(qg * NSPLIT + ksplit) * 256;
    mlp[w * 32 + q31] = m_;
    mlp[128 + w * 32 + q31] = l_;
  }
}

// ---------- merge the NSPLIT key-split partials + residual ----------
template <int NSPLIT, bool ALLBF>
__global__ __launch_bounds__(256) void merge_kernel(
    const unsigned short* __restrict__ Op, const float* __restrict__ ML,
    const unsigned short* __restrict__ Qb, float* __restrict__ out) {
  const float CS = 0.03125f * 1.4426950408889634f;
  const long gid = (long)blockIdx.x * 256 + threadIdx.x;
  const long idx = gid * 8;
  const int row = (int)(idx >> 8);
  const int qg = row >> 7, qr = row & 127;
  const float* mlb = ML + (long)(qg * NSPLIT) * 256;
  float mv[NSPLIT], lv[NSPLIT];
#pragma unroll
  for (int k = 0; k < NSPLIT; k++) {
    mv[k] = mlb[k * 256 + qr];
    lv[k] = mlb[k * 256 + 128 + qr];
  }
  float M = mv[0];
#pragma unroll
  for (int k = 1; k < NSPLIT; k++) M = fmaxf(M, mv[k]);
  float ek[NSPLIT], wsum = 0.f;
#pragma unroll
  for (int k = 0; k < NSPLIT; k++) {
    ek[k] = exp2f((mv[k] - M) * CS);
    wsum += ek[k] * lv[k];
  }
  const float inv = 1.0f / wsum;
  float acc[8];
  if (ALLBF) {
#pragma unroll
    for (int e = 0; e < 8; e++) acc[e] = 0.f;
#pragma unroll
    for (int k = 0; k < NSPLIT; k++) {
      u16x8 p = *(const u16x8*)(Op + (long)k * (16384 * 256) + idx);
#pragma unroll
      for (int e = 0; e < 8; e++) acc[e] += ek[k] * bf2f(p[e]);
    }
  } else {
    f32x4 pa = *(const f32x4*)(out + idx);
    f32x4 pb = *(const f32x4*)(out + idx + 4);
#pragma unroll
    for (int e = 0; e < 4; e++) {
      acc[e] = ek[NSPLIT - 1] * pa[e];
      acc[4 + e] = ek[NSPLIT - 1] * pb[e];
    }
#pragma unroll
    for (int k = 0; k < NSPLIT - 1; k++) {
      u16x8 p = *(const u16x8*)(Op + (long)k * (16384 * 256) + idx);
#pragma unroll
      for (int e = 0; e < 8; e++) acc[e] += ek[k] * bf2f(p[e]);
    }
  }
  u16x8 qv = *(const u16x8*)(Qb + idx);
  f32x4 ra, rb;
#pragma unroll
  for (int e = 0; e < 4; e++) ra[e] = acc[e] * inv + bf2f(qv[e]);
#pragma unroll
  for (int e = 0; e < 4; e++) rb[e] = acc[4 + e] * inv + bf2f(qv[4 + e]);
  *(f32x4*)(out + idx) = ra;
  *(f32x4*)(out + idx + 4) = rb;
}

extern "C" void kernel_launch(void* const* d_in, const int* in_sizes, int n_in,
                              void* d_out, int out_size, void* d_ws, size_t ws_size,
                              hipStream_t stream) {
  (void)in_sizes; (void)n_in; (void)out_size;
  const float* data1 = (const float*)d_in[0];  // [8,2048,1024]
  const float* data2 = (const float*)d_in[1];  // [8,2048,256]
  const float* Wq = (const float*)d_in[2];     // [1024,256]
  const float* bq = (const float*)d_in[3];     // [256]
  const float* Wk = (const float*)d_in[4];     // [256,256]
  const float* bk = (const float*)d_in[5];     // [256]
  float* out = (float*)d_out;                  // [8,2048,256] f32

  char* ws = (char*)d_ws;
  unsigned short* Qb  = (unsigned short*)(ws);                        // 8 MB
  unsigned short* Kb  = (unsigned short*)(ws + (8ull << 20));         // 8 MB
  unsigned short* KTb = (unsigned short*)(ws + (16ull << 20));        // 8 MB
  unsigned short* WqT = (unsigned short*)(ws + (24ull << 20));        // 512 KB
  unsigned short* WkT = (unsigned short*)(ws + (24ull << 20) + (512u << 10));  // 128 KB
  unsigned short* Op  = (unsigned short*)(ws + (25ull << 20));        // up to 4 x 8 MB

  wt2_kernel<<<dim3(1280), dim3(256), 0, stream>>>(Wq, WqT, Wk, WkT);
  proj2_kernel<<<dim3(1024), dim3(256), 0, stream>>>(data1, WqT, bq, Qb,
                                                     data2, WkT, bk, Kb, KTb);

  if (ws_size >= (58ull << 20)) {
    // all-bf16 partials: 4 x 8 MB at ws+25MB, ML at ws+57MB
    float* MLb = (float*)(ws + (57ull << 20));                        // 512 KB
    attn_kernel<4, true><<<dim3(512), dim3(256), 0, stream>>>(Qb, Kb, KTb, Op, out, MLb);
    merge_kernel<4, true><<<dim3(2048), dim3(256), 0, stream>>>(Op, MLb, Qb, out);
  } else if (ws_size >= (50ull << 20)) {
    float* MLb = (float*)(ws + (49ull << 20));                        // 512 KB
    attn_kernel<4, false><<<dim3(512), dim3(256), 0, stream>>>(Qb, Kb, KTb, Op, out, MLb);
    merge_kernel<4, false><<<dim3(2048), dim3(256), 0, stream>>>(Op, MLb, Qb, out);
  } else {
    float* MLb = (float*)(ws + (33ull << 20));                        // 256 KB
    attn_kernel<2, false><<<dim3(256), dim3(256), 0, stream>>>(Qb, Kb, KTb, Op, out, MLb);
    merge_kernel<2, false><<<dim3(2048), dim3(256), 0, stream>>>(Op, MLb, Qb, out);
  }
}